// Round 1
// baseline (236.277 us; speedup 1.0000x reference)
//
#include <hip/hip_runtime.h>
#include <hip/hip_bf16.h>
#include <math.h>

typedef __bf16 bf16;
typedef bf16 bf16x8 __attribute__((ext_vector_type(8)));
typedef bf16 bf16x4 __attribute__((ext_vector_type(4)));
typedef float f32x4 __attribute__((ext_vector_type(4)));

#define N_NODES 8192
#define DIN 256
#define DOUT 256
#define KCAT 512
#define EPSF 1e-8f

__device__ __forceinline__ f32x4 mfma16(bf16x8 a, bf16x8 b, f32x4 c) {
    return __builtin_amdgcn_mfma_f32_16x16x32_bf16(a, b, c, 0, 0, 0);
}

// ---------------- K0: W_w [256x256] -> WwT[n][k] bf16 ; W_fc [512x256] -> WfcT[n][k] bf16
__global__ __launch_bounds__(256) void k0_prep(const float* __restrict__ Ww,
                                               const float* __restrict__ Wfc,
                                               bf16* __restrict__ WwT,
                                               bf16* __restrict__ WfcT) {
    int tid = blockIdx.x * 256 + threadIdx.x;
    if (tid < 256 * 256) {
        int n = tid >> 8, k = tid & 255;
        WwT[n * 256 + k] = (bf16)Ww[k * 256 + n];
    }
    if (tid < 256 * 512) {
        int n = tid >> 9, k = tid & 511;
        WfcT[n * 512 + k] = (bf16)Wfc[k * 256 + n];
    }
}

// ---------------- K1: hT[col][m] = bf16(relu(X @ W_w + b_w))
// grid 512 blocks x 128 thr. Block = 16 rows; wave wid covers 128 cols.
__global__ __launch_bounds__(128) void k1_h(const float* __restrict__ X,
                                            const bf16* __restrict__ WwT,
                                            const float* __restrict__ bw,
                                            bf16* __restrict__ hT) {
    const int lane = threadIdx.x & 63;
    const int wid  = threadIdx.x >> 6;   // 0..1
    const int m0   = blockIdx.x * 16;
    const int lrow = lane & 15;
    const int lk8  = (lane >> 4) * 8;

    f32x4 acc[8];
#pragma unroll
    for (int i = 0; i < 8; ++i) acc[i] = {0.f, 0.f, 0.f, 0.f};

#pragma unroll
    for (int ks = 0; ks < DIN; ks += 32) {
        const float* xp = X + (size_t)(m0 + lrow) * DIN + ks + lk8;
        f32x4 x0 = *reinterpret_cast<const f32x4*>(xp);
        f32x4 x1 = *reinterpret_cast<const f32x4*>(xp + 4);
        bf16x8 a;
#pragma unroll
        for (int j = 0; j < 4; ++j) { a[j] = (bf16)x0[j]; a[4 + j] = (bf16)x1[j]; }
#pragma unroll
        for (int nb = 0; nb < 8; ++nb) {
            int col = wid * 128 + nb * 16 + lrow;
            bf16x8 b = *reinterpret_cast<const bf16x8*>(WwT + (size_t)col * DIN + ks + lk8);
            acc[nb] = mfma16(a, b, acc[nb]);
        }
    }
    const int mrow = m0 + (lane >> 4) * 4;
#pragma unroll
    for (int nb = 0; nb < 8; ++nb) {
        int col = wid * 128 + nb * 16 + lrow;
        float bias = bw[col];
        bf16x4 hv;
#pragma unroll
        for (int j = 0; j < 4; ++j) {
            float v = acc[nb][j] + bias;
            hv[j] = (bf16)(v > 0.f ? v : 0.f);
        }
        *reinterpret_cast<bf16x4*>(hT + (size_t)col * N_NODES + mrow) = hv;
    }
}

// ---------------- K2: pooled = (A @ h) / (rowsum(A)+eps), bf16 out
// grid 256 blocks x 512 thr (8 waves). Block = 32 rows x 256 cols.
// Wave wid owns cols [wid*32, wid*32+32): 2x2 fragments of 16x16.
// A: fp32 global -> cvt -> XOR-swizzled LDS (double-buffered, 1 barrier/iter).
// B: direct from hT (L2-resident), loaded exactly once per block.
// rowsum: extra MFMA with all-ones B fragment (wave 0 only).
__global__ __launch_bounds__(512) void k2_pool(const float* __restrict__ A,
                                               const bf16* __restrict__ hT,
                                               bf16* __restrict__ pooled) {
    __shared__ __align__(16) unsigned char As[2 * 4096];
    __shared__ float rs[32];
    const int t    = threadIdx.x;
    const int lane = t & 63;
    const int wid  = t >> 6;   // 0..7
    const int m0   = blockIdx.x * 32;
    const int lrow = lane & 15;
    const int lk8  = (lane >> 4) * 8;

    f32x4 acc[2][2];
    f32x4 sums[2];
#pragma unroll
    for (int i = 0; i < 2; ++i) {
        sums[i] = {0.f, 0.f, 0.f, 0.f};
#pragma unroll
        for (int j = 0; j < 2; ++j) acc[i][j] = {0.f, 0.f, 0.f, 0.f};
    }
    bf16x8 bOne;
#pragma unroll
    for (int j = 0; j < 8; ++j) bOne[j] = (bf16)1.0f;

    // staging: thread t handles row sr=t>>4, cols sc..sc+3 of the 32x64 fp32 tile
    const int sr = t >> 4;
    const int sc = (t & 15) * 4;
    const float* aSrc = A + (size_t)(m0 + sr) * N_NODES + sc;
    const int wByte = (sr * 128 + sc * 2) ^ ((sr & 7) << 4);

    int rByte[2][2];
#pragma unroll
    for (int mf = 0; mf < 2; ++mf)
#pragma unroll
        for (int kki = 0; kki < 2; ++kki) {
            int row = mf * 16 + lrow;
            rByte[mf][kki] = (row * 128 + (kki * 32 + lk8) * 2) ^ ((row & 7) << 4);
        }

    const bf16* bp0 = hT + (size_t)(wid * 32 + lrow) * N_NODES + lk8;
    const bf16* bp1 = bp0 + (size_t)16 * N_NODES;

    f32x4 regA = *reinterpret_cast<const f32x4*>(aSrc);
    const int NT = N_NODES / 64;
    for (int tile = 0; tile < NT; ++tile) {
        unsigned char* buf = As + (tile & 1) * 4096;
        bf16x4 w;
#pragma unroll
        for (int j = 0; j < 4; ++j) w[j] = (bf16)regA[j];
        *reinterpret_cast<bf16x4*>(buf + wByte) = w;
        if (tile + 1 < NT) regA = *reinterpret_cast<const f32x4*>(aSrc + (size_t)(tile + 1) * 64);
        __syncthreads();
        const int kg = tile * 64;
#pragma unroll
        for (int kki = 0; kki < 2; ++kki) {
            bf16x8 a0 = *reinterpret_cast<const bf16x8*>(buf + rByte[0][kki]);
            bf16x8 a1 = *reinterpret_cast<const bf16x8*>(buf + rByte[1][kki]);
            bf16x8 b0 = *reinterpret_cast<const bf16x8*>(bp0 + kg + kki * 32);
            bf16x8 b1 = *reinterpret_cast<const bf16x8*>(bp1 + kg + kki * 32);
            acc[0][0] = mfma16(a0, b0, acc[0][0]);
            acc[1][0] = mfma16(a1, b0, acc[1][0]);
            acc[0][1] = mfma16(a0, b1, acc[0][1]);
            acc[1][1] = mfma16(a1, b1, acc[1][1]);
            if (wid == 0) {
                sums[0] = mfma16(a0, bOne, sums[0]);
                sums[1] = mfma16(a1, bOne, sums[1]);
            }
        }
        // double-buffered: single barrier per iteration is sufficient
    }

    if (wid == 0 && lrow == 0) {
        int rbase = (lane >> 4) * 4;
#pragma unroll
        for (int j = 0; j < 4; ++j) {
            rs[rbase + j]      = sums[0][j];
            rs[16 + rbase + j] = sums[1][j];
        }
    }
    __syncthreads();
#pragma unroll
    for (int mf = 0; mf < 2; ++mf)
#pragma unroll
        for (int nb = 0; nb < 2; ++nb) {
            int col = wid * 32 + nb * 16 + lrow;
#pragma unroll
            for (int j = 0; j < 4; ++j) {
                int row = mf * 16 + (lane >> 4) * 4 + j;
                float v = acc[mf][nb][j] / (rs[row] + EPSF);
                pooled[(size_t)(m0 + row) * DOUT + col] = (bf16)v;
            }
        }
}

// ---------------- K3: out = relu([X || pooled] @ W_fc + b_fc) + eps, + per-block sumsq partial
// grid 512 blocks x 128 thr. Block = 16 rows; wave wid covers 128 cols.
__global__ __launch_bounds__(128) void k3_out(const float* __restrict__ X,
                                              const bf16* __restrict__ pooled,
                                              const bf16* __restrict__ WfcT,
                                              const float* __restrict__ bfc,
                                              float* __restrict__ out,
                                              float* __restrict__ partials) {
    const int lane = threadIdx.x & 63;
    const int wid  = threadIdx.x >> 6;
    const int m0   = blockIdx.x * 16;
    const int lrow = lane & 15;
    const int lk8  = (lane >> 4) * 8;

    f32x4 acc[8];
#pragma unroll
    for (int i = 0; i < 8; ++i) acc[i] = {0.f, 0.f, 0.f, 0.f};

    // k in [0,256): A-operand from X (fp32 -> bf16)
#pragma unroll
    for (int ks = 0; ks < 256; ks += 32) {
        const float* xp = X + (size_t)(m0 + lrow) * DIN + ks + lk8;
        f32x4 x0 = *reinterpret_cast<const f32x4*>(xp);
        f32x4 x1 = *reinterpret_cast<const f32x4*>(xp + 4);
        bf16x8 a;
#pragma unroll
        for (int j = 0; j < 4; ++j) { a[j] = (bf16)x0[j]; a[4 + j] = (bf16)x1[j]; }
#pragma unroll
        for (int nb = 0; nb < 8; ++nb) {
            int col = wid * 128 + nb * 16 + lrow;
            bf16x8 b = *reinterpret_cast<const bf16x8*>(WfcT + (size_t)col * KCAT + ks + lk8);
            acc[nb] = mfma16(a, b, acc[nb]);
        }
    }
    // k in [256,512): A-operand from pooled (bf16)
#pragma unroll
    for (int ks = 256; ks < 512; ks += 32) {
        bf16x8 a = *reinterpret_cast<const bf16x8*>(pooled + (size_t)(m0 + lrow) * DOUT + (ks - 256) + lk8);
#pragma unroll
        for (int nb = 0; nb < 8; ++nb) {
            int col = wid * 128 + nb * 16 + lrow;
            bf16x8 b = *reinterpret_cast<const bf16x8*>(WfcT + (size_t)col * KCAT + ks + lk8);
            acc[nb] = mfma16(a, b, acc[nb]);
        }
    }

    float ss = 0.f;
#pragma unroll
    for (int nb = 0; nb < 8; ++nb) {
        int col = wid * 128 + nb * 16 + lrow;
        float bias = bfc[col];
#pragma unroll
        for (int j = 0; j < 4; ++j) {
            int row = m0 + (lane >> 4) * 4 + j;
            float v = acc[nb][j] + bias;
            v = (v > 0.f ? v : 0.f) + EPSF;
            out[(size_t)row * DOUT + col] = v;
            ss += v * v;
        }
    }
#pragma unroll
    for (int off = 32; off; off >>= 1) ss += __shfl_xor(ss, off);
    __shared__ float sw[2];
    if (lane == 0) sw[wid] = ss;
    __syncthreads();
    if (threadIdx.x == 0) partials[blockIdx.x] = sw[0] + sw[1];
}

// ---------------- K4: deterministic reduce of 512 partials; scale out by 1/(norm+eps)
__global__ __launch_bounds__(256) void k4_norm(float* __restrict__ out,
                                               const float* __restrict__ partials) {
    __shared__ float sw[4];
    float s = partials[threadIdx.x] + partials[threadIdx.x + 256];
#pragma unroll
    for (int off = 32; off; off >>= 1) s += __shfl_xor(s, off);
    if ((threadIdx.x & 63) == 0) sw[threadIdx.x >> 6] = s;
    __syncthreads();
    float total = sw[0] + sw[1] + sw[2] + sw[3];
    float scale = 1.f / (sqrtf(total) + EPSF);
    f32x4* o4 = reinterpret_cast<f32x4*>(out);
    const int nvec = N_NODES * DOUT / 4;
    for (int i = blockIdx.x * blockDim.x + threadIdx.x; i < nvec; i += gridDim.x * blockDim.x) {
        f32x4 v = o4[i];
#pragma unroll
        for (int j = 0; j < 4; ++j) v[j] *= scale;
        o4[i] = v;
    }
}

extern "C" void kernel_launch(void* const* d_in, const int* in_sizes, int n_in,
                              void* d_out, int out_size, void* d_ws, size_t ws_size,
                              hipStream_t stream) {
    const float* A   = (const float*)d_in[0];
    const float* X   = (const float*)d_in[1];
    const float* Ww  = (const float*)d_in[2];
    const float* bw  = (const float*)d_in[3];
    const float* Wfc = (const float*)d_in[4];
    const float* bfc = (const float*)d_in[5];
    float* out = (float*)d_out;

    char* ws = (char*)d_ws;
    bf16*  hT       = (bf16*)(ws);                                  // 4 MiB
    bf16*  pooled   = (bf16*)(ws + (4u << 20));                     // 4 MiB
    bf16*  WwT      = (bf16*)(ws + (8u << 20));                     // 128 KiB
    bf16*  WfcT     = (bf16*)(ws + (8u << 20) + (128u << 10));      // 256 KiB
    float* partials = (float*)(ws + (8u << 20) + (384u << 10));     // 2 KiB

    k0_prep<<<512, 256, 0, stream>>>(Ww, Wfc, WwT, WfcT);
    k1_h<<<512, 128, 0, stream>>>(X, WwT, bw, hT);
    k2_pool<<<256, 512, 0, stream>>>(A, hT, pooled);
    k3_out<<<512, 128, 0, stream>>>(X, pooled, WfcT, bfc, out, partials);
    k4_norm<<<256, 256, 0, stream>>>(out, partials);
}